// Round 1
// baseline (1280.116 us; speedup 1.0000x reference)
//
#include <hip/hip_runtime.h>
#include <hip/hip_bf16.h>

#define TABN   4096
#define ROWS   (TABN + 1)           // table rows per interaction
#define DMAX   6.5f
#define DELTA  (DMAX / (float)TABN)
#define INVD   ((float)TABN / DMAX)
#define LOG2F_ 0.6931471805599453f

__device__ __forceinline__ float ssp(float x) {
    // shifted softplus, numerically stable: log(1+e^x) - log(2)
    return fmaxf(x, 0.f) + log1pf(expf(-fabsf(x))) - LOG2F_;
}

// ---------------- filter lookup table: W_i(d) for d = t*DELTA ----------------
__global__ void ftab_kernel(const float* __restrict__ fw1, const float* __restrict__ fb1,
                            const float* __restrict__ fw2, const float* __restrict__ fb2,
                            float* __restrict__ ftab) {
    int t = blockIdx.x;          // 0..ROWS-1
    int i = blockIdx.y;          // interaction 0/1
    int j = threadIdx.x;         // 0..63 channel
    float d = (float)t * DELTA;
    float acc = fb1[i * 64 + j];
    for (int k = 0; k < 51; ++k) {
        float u = d - 0.1f * (float)k;
        float r = expf(-10.f * u * u);
        acc = fmaf(r, fw1[((size_t)i * 51 + k) * 64 + j], acc);
    }
    __shared__ float h[64];
    h[j] = ssp(acc);
    __syncthreads();
    float o = fb2[i * 64 + j];
    for (int k = 0; k < 64; ++k)
        o = fmaf(h[k], fw2[((size_t)i * 64 + k) * 64 + j], o);
    ftab[((size_t)i * ROWS + t) * 64 + j] = o;
}

// ---------------- per-edge distance + histogram of tgt ----------------
__global__ void edge_d_kernel(const float* __restrict__ pos, const int* __restrict__ ei,
                              float* __restrict__ d_arr, int* __restrict__ counts, int E) {
    int e = blockIdx.x * blockDim.x + threadIdx.x;
    if (e >= E) return;
    int s = ei[e], t = ei[E + e];
    float dx = pos[3 * s]     - pos[3 * t];
    float dy = pos[3 * s + 1] - pos[3 * t + 1];
    float dz = pos[3 * s + 2] - pos[3 * t + 2];
    d_arr[e] = sqrtf(dx * dx + dy * dy + dz * dz);
    atomicAdd(&counts[t], 1);
}

// ---------------- single-block exclusive scan over counts[n] ----------------
__global__ void scan_kernel(const int* __restrict__ counts, int* __restrict__ off,
                            int* __restrict__ cursor, int n) {
    __shared__ int sums[1024];
    int tid = threadIdx.x;
    const int CH = (n + 1023) >> 10;
    int base = tid * CH;
    int s = 0;
    for (int i = 0; i < CH; ++i) { int idx = base + i; if (idx < n) s += counts[idx]; }
    sums[tid] = s;
    __syncthreads();
    for (int o = 1; o < 1024; o <<= 1) {
        int v = (tid >= o) ? sums[tid - o] : 0;
        __syncthreads();
        sums[tid] += v;
        __syncthreads();
    }
    int run = sums[tid] - s;   // exclusive prefix of this chunk
    for (int i = 0; i < CH; ++i) {
        int idx = base + i;
        if (idx < n) { off[idx] = run; cursor[idx] = run; run += counts[idx]; }
    }
    if (tid == 1023) off[n] = sums[1023];
}

// ---------------- scatter edges into tgt-sorted order ----------------
__global__ void scatter_kernel(const int* __restrict__ ei, const float* __restrict__ d_arr,
                               int* __restrict__ cursor, int* __restrict__ src_s,
                               float* __restrict__ d_s, int E) {
    int e = blockIdx.x * blockDim.x + threadIdx.x;
    if (e >= E) return;
    int t = ei[E + e];
    int p = atomicAdd(&cursor[t], 1);
    src_s[p] = ei[e];
    d_s[p]   = d_arr[e];
}

// ---------------- x = emb_z[z] ----------------
__global__ void embed_kernel(const int* __restrict__ z, const float* __restrict__ emb,
                             float* __restrict__ x, int n) {
    int idx = blockIdx.x * blockDim.x + threadIdx.x;   // over n*16 float4 chunks
    if (idx >= n * 16) return;
    int node = idx >> 4, c = idx & 15;
    ((float4*)x)[idx] = ((const float4*)emb)[z[node] * 16 + c];
}

// ---------------- solvent head for the 4 unique solvent rows ----------------
__global__ void solv_kernel(const float* __restrict__ emb_solv,
                            const float* __restrict__ w1, const float* __restrict__ b1,
                            const float* __restrict__ w2, const float* __restrict__ b2,
                            float* __restrict__ s4) {
    __shared__ float h[4][64];
    int t = threadIdx.x, r = t >> 6, j = t & 63;
    float acc = b1[j];
    for (int k = 0; k < 64; ++k) acc = fmaf(emb_solv[r * 64 + k], w1[k * 64 + j], acc);
    h[r][j] = ssp(acc);
    __syncthreads();
    if (j < 32) {
        float a = b2[j];
        for (int k = 0; k < 64; ++k) a = fmaf(h[r][k], w2[k * 32 + j], a);
        s4[r * 32 + j] = a;
    }
}

// ---------------- generic [n,64]@[64,64]+b row matmul, opt ssp / residual ----
template <bool ACT, bool RES>
__global__ void mm64_kernel(const float* __restrict__ in, const float* __restrict__ w,
                            const float* __restrict__ b, const float* __restrict__ res,
                            float* __restrict__ out, int n) {
    __shared__ float sw[64 * 64];
    int tid = threadIdx.x;
    for (int i = tid; i < 4096; i += 256) sw[i] = w[i];
    __syncthreads();
    int node = blockIdx.x * 256 + tid;
    if (node >= n) return;
    float x[64];
    const float4* in4 = (const float4*)(in + (size_t)node * 64);
#pragma unroll
    for (int c = 0; c < 16; ++c) {
        float4 v = in4[c];
        x[4 * c] = v.x; x[4 * c + 1] = v.y; x[4 * c + 2] = v.z; x[4 * c + 3] = v.w;
    }
    const float4* b4 = (const float4*)b;
    const float4* r4 = (const float4*)(res + (size_t)node * 64);
    float4* o4 = (float4*)(out + (size_t)node * 64);
    for (int jg = 0; jg < 16; ++jg) {
        float4 acc = b4[jg];
#pragma unroll
        for (int k = 0; k < 64; ++k) {
            float4 wv = *(const float4*)(sw + k * 64 + jg * 4);
            acc.x = fmaf(x[k], wv.x, acc.x);
            acc.y = fmaf(x[k], wv.y, acc.y);
            acc.z = fmaf(x[k], wv.z, acc.z);
            acc.w = fmaf(x[k], wv.w, acc.w);
        }
        if constexpr (ACT) {
            acc.x = ssp(acc.x); acc.y = ssp(acc.y); acc.z = ssp(acc.z); acc.w = ssp(acc.w);
        }
        if constexpr (RES) {
            float4 rv = r4[jg];
            acc.x += rv.x; acc.y += rv.y; acc.z += rv.z; acc.w += rv.w;
        }
        o4[jg] = acc;
    }
}

// ---------------- per-node aggregation: agg[t] = sum_e m[src]*W(d) ----------
__global__ void agg_kernel(const int* __restrict__ off, const int* __restrict__ src_s,
                           const float* __restrict__ d_s, const float* __restrict__ m,
                           const float* __restrict__ ftab, float* __restrict__ agg, int n) {
    int wave = (blockIdx.x * blockDim.x + threadIdx.x) >> 6;
    int lane = threadIdx.x & 63;
    if (wave >= n) return;
    int e0 = off[wave], e1 = off[wave + 1];
    float acc = 0.f;
    for (int e = e0; e < e1; ++e) {
        int   s  = src_s[e];
        float dd = d_s[e];
        float ds = fminf(dd, DMAX) * INVD;
        int   ti = (int)ds;
        ti = min(ti, TABN - 1);
        float fr = ds - (float)ti;
        const float* r0 = ftab + (size_t)ti * 64 + lane;
        float w0 = r0[0], w1 = r0[64];
        float w = fmaf(fr, w1 - w0, w0);
        acc = fmaf(m[(size_t)s * 64 + lane], w, acc);
    }
    agg[(size_t)wave * 64 + lane] = acc;
}

// ---------------- scatter-mean pooling via binary search (batch sorted) -----
__global__ void pool_kernel(const float* __restrict__ h, const int* __restrict__ batch,
                            float* __restrict__ pooled, int n_nodes) {
    int g = blockIdx.x, j = threadIdx.x;   // block = 64
    int lo = 0, hi = n_nodes;
    while (lo < hi) { int mid = (lo + hi) >> 1; if (batch[mid] < g) lo = mid + 1; else hi = mid; }
    int start = lo;
    int lo2 = start, hi2 = n_nodes;
    while (lo2 < hi2) { int mid = (lo2 + hi2) >> 1; if (batch[mid] < g + 1) lo2 = mid + 1; else hi2 = mid; }
    int end = lo2;
    float acc = 0.f;
    for (int r = start; r < end; ++r) acc += h[(size_t)r * 64 + j];
    float cnt = (float)(end - start);
    pooled[(size_t)g * 64 + j] = acc / fmaxf(cnt, 1.f);
}

// ---------------- final graph head: 96 -> 128 -> 32 -> 1 --------------------
__global__ void post2_kernel(const float* __restrict__ pooled, const float* __restrict__ s4,
                             const int* __restrict__ solvent,
                             const float* __restrict__ w1, const float* __restrict__ b1,
                             const float* __restrict__ w2, const float* __restrict__ b2,
                             const float* __restrict__ w3, const float* __restrict__ b3,
                             float* __restrict__ out) {
    __shared__ float in96[96];
    __shared__ float l1[128];
    __shared__ float l2[32];
    int g = blockIdx.x, t = threadIdx.x;   // block = 128
    if (t < 64)      in96[t] = pooled[(size_t)g * 64 + t];
    else if (t < 96) in96[t] = s4[solvent[g] * 32 + (t - 64)];
    __syncthreads();
    float acc = b1[t];
    for (int k = 0; k < 96; ++k) acc = fmaf(in96[k], w1[k * 128 + t], acc);
    l1[t] = ssp(acc);
    __syncthreads();
    if (t < 32) {
        float a = b2[t];
        for (int k = 0; k < 128; ++k) a = fmaf(l1[k], w2[k * 32 + t], a);
        l2[t] = ssp(a);
    }
    __syncthreads();
    if (t < 32) {
        float p = l2[t] * w3[t];
        for (int o = 16; o >= 1; o >>= 1) p += __shfl_down(p, o);
        if (t == 0) out[g] = p + b3[0];
    }
}

extern "C" void kernel_launch(void* const* d_in, const int* in_sizes, int n_in,
                              void* d_out, int out_size, void* d_ws, size_t ws_size,
                              hipStream_t stream) {
    const float* pos      = (const float*)d_in[0];
    const int*   ei       = (const int*)d_in[1];
    const int*   z        = (const int*)d_in[2];
    const int*   batch    = (const int*)d_in[3];
    const int*   solvent  = (const int*)d_in[4];
    const float* emb_z    = (const float*)d_in[5];
    const float* emb_solv = (const float*)d_in[6];
    const float* solv_w1  = (const float*)d_in[7];  const float* solv_b1 = (const float*)d_in[8];
    const float* solv_w2  = (const float*)d_in[9];  const float* solv_b2 = (const float*)d_in[10];
    const float* lin1_w   = (const float*)d_in[11]; const float* lin1_b  = (const float*)d_in[12];
    const float* mlp_w1   = (const float*)d_in[13]; const float* mlp_b1  = (const float*)d_in[14];
    const float* mlp_w2   = (const float*)d_in[15]; const float* mlp_b2  = (const float*)d_in[16];
    const float* filt_w1  = (const float*)d_in[17]; const float* filt_b1 = (const float*)d_in[18];
    const float* filt_w2  = (const float*)d_in[19]; const float* filt_b2 = (const float*)d_in[20];
    const float* post_w1  = (const float*)d_in[21]; const float* post_b1 = (const float*)d_in[22];
    const float* post_w2  = (const float*)d_in[23]; const float* post_b2 = (const float*)d_in[24];
    const float* p2w1 = (const float*)d_in[25]; const float* p2b1 = (const float*)d_in[26];
    const float* p2w2 = (const float*)d_in[27]; const float* p2b2 = (const float*)d_in[28];
    const float* p2w3 = (const float*)d_in[29]; const float* p2b3 = (const float*)d_in[30];
    float* out = (float*)d_out;

    const int N = in_sizes[2];
    const int E = in_sizes[1] / 2;
    const int G = in_sizes[4];

    char* wp = (char*)d_ws;
    auto alloc = [&](size_t bytes) -> void* {
        void* r = (void*)wp;
        wp += (bytes + 255) & ~(size_t)255;
        return r;
    };
    float* d_edge = (float*)alloc((size_t)E * 4);
    int*   src_s  = (int*)  alloc((size_t)E * 4);
    float* d_s    = (float*)alloc((size_t)E * 4);
    int*   counts = (int*)  alloc((size_t)N * 4);
    int*   off    = (int*)  alloc((size_t)(N + 1) * 4);
    int*   cursor = (int*)  alloc((size_t)N * 4);
    float* ftab   = (float*)alloc((size_t)2 * ROWS * 64 * 4);
    float* s4     = (float*)alloc(4 * 32 * 4);
    float* x      = (float*)alloc((size_t)N * 64 * 4);
    float* m      = (float*)alloc((size_t)N * 64 * 4);
    float* agg    = (float*)alloc((size_t)N * 64 * 4);
    float* pooled = (float*)alloc((size_t)G * 64 * 4);
    (void)ws_size; (void)n_in; (void)out_size;

    hipMemsetAsync(counts, 0, (size_t)N * 4, stream);

    ftab_kernel<<<dim3(ROWS, 2), 64, 0, stream>>>(filt_w1, filt_b1, filt_w2, filt_b2, ftab);
    edge_d_kernel<<<(E + 255) / 256, 256, 0, stream>>>(pos, ei, d_edge, counts, E);
    scan_kernel<<<1, 1024, 0, stream>>>(counts, off, cursor, N);
    scatter_kernel<<<(E + 255) / 256, 256, 0, stream>>>(ei, d_edge, cursor, src_s, d_s, E);
    embed_kernel<<<((size_t)N * 16 + 255) / 256, 256, 0, stream>>>(z, emb_z, x, N);
    solv_kernel<<<1, 256, 0, stream>>>(emb_solv, solv_w1, solv_b1, solv_w2, solv_b2, s4);

    int mmg = (N + 255) / 256;
    for (int i = 0; i < 2; ++i) {
        mm64_kernel<false, false><<<mmg, 256, 0, stream>>>(x, lin1_w + (size_t)i * 4096,
                                                           lin1_b + i * 64, nullptr, m, N);
        agg_kernel<<<(N + 3) / 4, 256, 0, stream>>>(off, src_s, d_s, m,
                                                    ftab + (size_t)i * ROWS * 64, agg, N);
        mm64_kernel<true, false><<<mmg, 256, 0, stream>>>(agg, mlp_w1 + (size_t)i * 4096,
                                                          mlp_b1 + i * 64, nullptr, agg, N);
        mm64_kernel<false, true><<<mmg, 256, 0, stream>>>(agg, mlp_w2 + (size_t)i * 4096,
                                                          mlp_b2 + i * 64, x, x, N);
    }
    // post MLP: h = ssp(x@pw1+b1)@pw2+b2   (x dead afterwards, reuse buffers)
    mm64_kernel<true, false><<<mmg, 256, 0, stream>>>(x, post_w1, post_b1, nullptr, x, N);
    mm64_kernel<false, false><<<mmg, 256, 0, stream>>>(x, post_w2, post_b2, nullptr, m, N);

    pool_kernel<<<G, 64, 0, stream>>>(m, batch, pooled, N);
    post2_kernel<<<G, 128, 0, stream>>>(pooled, s4, solvent, p2w1, p2b1, p2w2, p2b2,
                                        p2w3, p2b3, out);
}

// Round 2
// 1041.330 us; speedup vs baseline: 1.2293x; 1.2293x over previous
//
#include <hip/hip_runtime.h>
#include <hip/hip_bf16.h>

#define TABN   4096
#define ROWS   (TABN + 1)           // table rows per interaction
#define DMAX   6.5f
#define DELTA  (DMAX / (float)TABN)
#define INVD   ((float)TABN / DMAX)
#define LOG2F_ 0.6931471805599453f

__device__ __forceinline__ float ssp(float x) {
    // shifted softplus, numerically stable: log(1+e^x) - log(2)
    return fmaxf(x, 0.f) + log1pf(expf(-fabsf(x))) - LOG2F_;
}

// ---------------- filter lookup table: W_i(d) for d = t*DELTA ----------------
__global__ void ftab_kernel(const float* __restrict__ fw1, const float* __restrict__ fb1,
                            const float* __restrict__ fw2, const float* __restrict__ fb2,
                            float* __restrict__ ftab) {
    int t = blockIdx.x;          // 0..ROWS-1
    int i = blockIdx.y;          // interaction 0/1
    int j = threadIdx.x;         // 0..63 channel
    float d = (float)t * DELTA;
    float acc = fb1[i * 64 + j];
    for (int k = 0; k < 51; ++k) {
        float u = d - 0.1f * (float)k;
        float r = expf(-10.f * u * u);
        acc = fmaf(r, fw1[((size_t)i * 51 + k) * 64 + j], acc);
    }
    __shared__ float h[64];
    h[j] = ssp(acc);
    __syncthreads();
    float o = fb2[i * 64 + j];
    for (int k = 0; k < 64; ++k)
        o = fmaf(h[k], fw2[((size_t)i * 64 + k) * 64 + j], o);
    ftab[((size_t)i * ROWS + t) * 64 + j] = o;
}

// ---------------- per-edge distance + histogram of tgt ----------------
__global__ void edge_d_kernel(const float* __restrict__ pos, const int* __restrict__ ei,
                              float* __restrict__ d_arr, int* __restrict__ counts, int E) {
    int e = blockIdx.x * blockDim.x + threadIdx.x;
    if (e >= E) return;
    int s = ei[e], t = ei[E + e];
    float dx = pos[3 * s]     - pos[3 * t];
    float dy = pos[3 * s + 1] - pos[3 * t + 1];
    float dz = pos[3 * s + 2] - pos[3 * t + 2];
    d_arr[e] = sqrtf(dx * dx + dy * dy + dz * dz);
    atomicAdd(&counts[t], 1);
}

// ---------------- hierarchical exclusive scan over counts[n] ----------------
// scan1: per-block (1024 elems) totals
__global__ void scan1_kernel(const int* __restrict__ counts, int* __restrict__ bsums, int n) {
    int tid = threadIdx.x;
    int base = blockIdx.x * 1024 + tid * 4;
    int s = 0;
#pragma unroll
    for (int i = 0; i < 4; ++i) { int idx = base + i; if (idx < n) s += counts[idx]; }
    __shared__ int sm[256];
    sm[tid] = s;
    __syncthreads();
    for (int o = 128; o >= 1; o >>= 1) {
        if (tid < o) sm[tid] += sm[tid + o];
        __syncthreads();
    }
    if (tid == 0) bsums[blockIdx.x] = sm[0];
}

// scan2: single small block exclusive-scans the <=1024 block totals in place
__global__ void scan2_kernel(int* __restrict__ bsums, int nb) {
    __shared__ int sm[1024];
    int tid = threadIdx.x;
    int v = (tid < nb) ? bsums[tid] : 0;
    sm[tid] = v;
    __syncthreads();
    for (int o = 1; o < 1024; o <<= 1) {
        int t = (tid >= o) ? sm[tid - o] : 0;
        __syncthreads();
        sm[tid] += t;
        __syncthreads();
    }
    if (tid < nb) bsums[tid] = sm[tid] - v;   // exclusive
}

// scan3: recompute in-block exclusive scan, add block base, emit off/cursor
__global__ void scan3_kernel(const int* __restrict__ counts, const int* __restrict__ bsums,
                             int* __restrict__ off, int* __restrict__ cursor, int n) {
    int tid = threadIdx.x;
    int base = blockIdx.x * 1024 + tid * 4;
    int c[4];
    int s = 0;
#pragma unroll
    for (int i = 0; i < 4; ++i) {
        int idx = base + i;
        c[i] = (idx < n) ? counts[idx] : 0;
        s += c[i];
    }
    __shared__ int sm[256];
    sm[tid] = s;
    __syncthreads();
    for (int o = 1; o < 256; o <<= 1) {
        int t = (tid >= o) ? sm[tid - o] : 0;
        __syncthreads();
        sm[tid] += t;
        __syncthreads();
    }
    int run = bsums[blockIdx.x] + sm[tid] - s;   // exclusive prefix of this thread
#pragma unroll
    for (int i = 0; i < 4; ++i) {
        int idx = base + i;
        if (idx < n) { off[idx] = run; cursor[idx] = run; run += c[i]; }
    }
    if (blockIdx.x == gridDim.x - 1 && tid == 255) off[n] = run;
}

// ---------------- scatter edges into tgt-sorted order ----------------
__global__ void scatter_kernel(const int* __restrict__ ei, const float* __restrict__ d_arr,
                               int* __restrict__ cursor, int* __restrict__ src_s,
                               float* __restrict__ d_s, int E) {
    int e = blockIdx.x * blockDim.x + threadIdx.x;
    if (e >= E) return;
    int t = ei[E + e];
    int p = atomicAdd(&cursor[t], 1);
    src_s[p] = ei[e];
    d_s[p]   = d_arr[e];
}

// ---------------- x = emb_z[z] ----------------
__global__ void embed_kernel(const int* __restrict__ z, const float* __restrict__ emb,
                             float* __restrict__ x, int n) {
    int idx = blockIdx.x * blockDim.x + threadIdx.x;   // over n*16 float4 chunks
    if (idx >= n * 16) return;
    int node = idx >> 4, c = idx & 15;
    ((float4*)x)[idx] = ((const float4*)emb)[z[node] * 16 + c];
}

// ---------------- solvent head for the 4 unique solvent rows ----------------
__global__ void solv_kernel(const float* __restrict__ emb_solv,
                            const float* __restrict__ w1, const float* __restrict__ b1,
                            const float* __restrict__ w2, const float* __restrict__ b2,
                            float* __restrict__ s4) {
    __shared__ float h[4][64];
    int t = threadIdx.x, r = t >> 6, j = t & 63;
    float acc = b1[j];
    for (int k = 0; k < 64; ++k) acc = fmaf(emb_solv[r * 64 + k], w1[k * 64 + j], acc);
    h[r][j] = ssp(acc);
    __syncthreads();
    if (j < 32) {
        float a = b2[j];
        for (int k = 0; k < 64; ++k) a = fmaf(h[r][k], w2[k * 32 + j], a);
        s4[r * 32 + j] = a;
    }
}

// ---------------- generic [n,64]@[64,64]+b row matmul, opt ssp / residual ----
template <bool ACT, bool RES>
__global__ void mm64_kernel(const float* __restrict__ in, const float* __restrict__ w,
                            const float* __restrict__ b, const float* __restrict__ res,
                            float* __restrict__ out, int n) {
    __shared__ float sw[64 * 64];
    int tid = threadIdx.x;
    for (int i = tid; i < 4096; i += 256) sw[i] = w[i];
    __syncthreads();
    int node = blockIdx.x * 256 + tid;
    if (node >= n) return;
    float x[64];
    const float4* in4 = (const float4*)(in + (size_t)node * 64);
#pragma unroll
    for (int c = 0; c < 16; ++c) {
        float4 v = in4[c];
        x[4 * c] = v.x; x[4 * c + 1] = v.y; x[4 * c + 2] = v.z; x[4 * c + 3] = v.w;
    }
    const float4* b4 = (const float4*)b;
    const float4* r4 = (const float4*)(res + (size_t)node * 64);
    float4* o4 = (float4*)(out + (size_t)node * 64);
    for (int jg = 0; jg < 16; ++jg) {
        float4 acc = b4[jg];
#pragma unroll
        for (int k = 0; k < 64; ++k) {
            float4 wv = *(const float4*)(sw + k * 64 + jg * 4);
            acc.x = fmaf(x[k], wv.x, acc.x);
            acc.y = fmaf(x[k], wv.y, acc.y);
            acc.z = fmaf(x[k], wv.z, acc.z);
            acc.w = fmaf(x[k], wv.w, acc.w);
        }
        if constexpr (ACT) {
            acc.x = ssp(acc.x); acc.y = ssp(acc.y); acc.z = ssp(acc.z); acc.w = ssp(acc.w);
        }
        if constexpr (RES) {
            float4 rv = r4[jg];
            acc.x += rv.x; acc.y += rv.y; acc.z += rv.z; acc.w += rv.w;
        }
        o4[jg] = acc;
    }
}

// ---------------- per-node aggregation: agg[t] = sum_e m[src]*W(d) ----------
__global__ void agg_kernel(const int* __restrict__ off, const int* __restrict__ src_s,
                           const float* __restrict__ d_s, const float* __restrict__ m,
                           const float* __restrict__ ftab, float* __restrict__ agg, int n) {
    int wave = (blockIdx.x * blockDim.x + threadIdx.x) >> 6;
    int lane = threadIdx.x & 63;
    if (wave >= n) return;
    int e0 = off[wave], e1 = off[wave + 1];
    float acc = 0.f;
    for (int e = e0; e < e1; ++e) {
        int   s  = src_s[e];
        float dd = d_s[e];
        float ds = fminf(dd, DMAX) * INVD;
        int   ti = (int)ds;
        ti = min(ti, TABN - 1);
        float fr = ds - (float)ti;
        const float* r0 = ftab + (size_t)ti * 64 + lane;
        float w0 = r0[0], w1 = r0[64];
        float w = fmaf(fr, w1 - w0, w0);
        acc = fmaf(m[(size_t)s * 64 + lane], w, acc);
    }
    agg[(size_t)wave * 64 + lane] = acc;
}

// ---------------- scatter-mean pooling via binary search (batch sorted) -----
__global__ void pool_kernel(const float* __restrict__ h, const int* __restrict__ batch,
                            float* __restrict__ pooled, int n_nodes) {
    int g = blockIdx.x, j = threadIdx.x;   // block = 64
    int lo = 0, hi = n_nodes;
    while (lo < hi) { int mid = (lo + hi) >> 1; if (batch[mid] < g) lo = mid + 1; else hi = mid; }
    int start = lo;
    int lo2 = start, hi2 = n_nodes;
    while (lo2 < hi2) { int mid = (lo2 + hi2) >> 1; if (batch[mid] < g + 1) lo2 = mid + 1; else hi2 = mid; }
    int end = lo2;
    float acc = 0.f;
    for (int r = start; r < end; ++r) acc += h[(size_t)r * 64 + j];
    float cnt = (float)(end - start);
    pooled[(size_t)g * 64 + j] = acc / fmaxf(cnt, 1.f);
}

// ---------------- final graph head: 96 -> 128 -> 32 -> 1 --------------------
__global__ void post2_kernel(const float* __restrict__ pooled, const float* __restrict__ s4,
                             const int* __restrict__ solvent,
                             const float* __restrict__ w1, const float* __restrict__ b1,
                             const float* __restrict__ w2, const float* __restrict__ b2,
                             const float* __restrict__ w3, const float* __restrict__ b3,
                             float* __restrict__ out) {
    __shared__ float in96[96];
    __shared__ float l1[128];
    __shared__ float l2[32];
    int g = blockIdx.x, t = threadIdx.x;   // block = 128
    if (t < 64)      in96[t] = pooled[(size_t)g * 64 + t];
    else if (t < 96) in96[t] = s4[solvent[g] * 32 + (t - 64)];
    __syncthreads();
    float acc = b1[t];
    for (int k = 0; k < 96; ++k) acc = fmaf(in96[k], w1[k * 128 + t], acc);
    l1[t] = ssp(acc);
    __syncthreads();
    if (t < 32) {
        float a = b2[t];
        for (int k = 0; k < 128; ++k) a = fmaf(l1[k], w2[k * 32 + t], a);
        l2[t] = ssp(a);
    }
    __syncthreads();
    if (t < 32) {
        float p = l2[t] * w3[t];
        for (int o = 16; o >= 1; o >>= 1) p += __shfl_down(p, o);
        if (t == 0) out[g] = p + b3[0];
    }
}

extern "C" void kernel_launch(void* const* d_in, const int* in_sizes, int n_in,
                              void* d_out, int out_size, void* d_ws, size_t ws_size,
                              hipStream_t stream) {
    const float* pos      = (const float*)d_in[0];
    const int*   ei       = (const int*)d_in[1];
    const int*   z        = (const int*)d_in[2];
    const int*   batch    = (const int*)d_in[3];
    const int*   solvent  = (const int*)d_in[4];
    const float* emb_z    = (const float*)d_in[5];
    const float* emb_solv = (const float*)d_in[6];
    const float* solv_w1  = (const float*)d_in[7];  const float* solv_b1 = (const float*)d_in[8];
    const float* solv_w2  = (const float*)d_in[9];  const float* solv_b2 = (const float*)d_in[10];
    const float* lin1_w   = (const float*)d_in[11]; const float* lin1_b  = (const float*)d_in[12];
    const float* mlp_w1   = (const float*)d_in[13]; const float* mlp_b1  = (const float*)d_in[14];
    const float* mlp_w2   = (const float*)d_in[15]; const float* mlp_b2  = (const float*)d_in[16];
    const float* filt_w1  = (const float*)d_in[17]; const float* filt_b1 = (const float*)d_in[18];
    const float* filt_w2  = (const float*)d_in[19]; const float* filt_b2 = (const float*)d_in[20];
    const float* post_w1  = (const float*)d_in[21]; const float* post_b1 = (const float*)d_in[22];
    const float* post_w2  = (const float*)d_in[23]; const float* post_b2 = (const float*)d_in[24];
    const float* p2w1 = (const float*)d_in[25]; const float* p2b1 = (const float*)d_in[26];
    const float* p2w2 = (const float*)d_in[27]; const float* p2b2 = (const float*)d_in[28];
    const float* p2w3 = (const float*)d_in[29]; const float* p2b3 = (const float*)d_in[30];
    float* out = (float*)d_out;

    const int N = in_sizes[2];
    const int E = in_sizes[1] / 2;
    const int G = in_sizes[4];

    char* wp = (char*)d_ws;
    auto alloc = [&](size_t bytes) -> void* {
        void* r = (void*)wp;
        wp += (bytes + 255) & ~(size_t)255;
        return r;
    };
    float* d_edge = (float*)alloc((size_t)E * 4);
    int*   src_s  = (int*)  alloc((size_t)E * 4);
    float* d_s    = (float*)alloc((size_t)E * 4);
    int*   counts = (int*)  alloc((size_t)N * 4);
    int*   off    = (int*)  alloc((size_t)(N + 1) * 4);
    int*   cursor = (int*)  alloc((size_t)N * 4);
    int*   bsums  = (int*)  alloc(1024 * 4);
    float* ftab   = (float*)alloc((size_t)2 * ROWS * 64 * 4);
    float* s4     = (float*)alloc(4 * 32 * 4);
    float* x      = (float*)alloc((size_t)N * 64 * 4);
    float* m      = (float*)alloc((size_t)N * 64 * 4);
    float* agg    = (float*)alloc((size_t)N * 64 * 4);
    float* pooled = (float*)alloc((size_t)G * 64 * 4);
    (void)ws_size; (void)n_in; (void)out_size;

    hipMemsetAsync(counts, 0, (size_t)N * 4, stream);

    ftab_kernel<<<dim3(ROWS, 2), 64, 0, stream>>>(filt_w1, filt_b1, filt_w2, filt_b2, ftab);
    edge_d_kernel<<<(E + 255) / 256, 256, 0, stream>>>(pos, ei, d_edge, counts, E);
    int nb = (N + 1023) / 1024;
    scan1_kernel<<<nb, 256, 0, stream>>>(counts, bsums, N);
    scan2_kernel<<<1, 1024, 0, stream>>>(bsums, nb);
    scan3_kernel<<<nb, 256, 0, stream>>>(counts, bsums, off, cursor, N);
    scatter_kernel<<<(E + 255) / 256, 256, 0, stream>>>(ei, d_edge, cursor, src_s, d_s, E);
    embed_kernel<<<((size_t)N * 16 + 255) / 256, 256, 0, stream>>>(z, emb_z, x, N);
    solv_kernel<<<1, 256, 0, stream>>>(emb_solv, solv_w1, solv_b1, solv_w2, solv_b2, s4);

    int mmg = (N + 255) / 256;
    for (int i = 0; i < 2; ++i) {
        mm64_kernel<false, false><<<mmg, 256, 0, stream>>>(x, lin1_w + (size_t)i * 4096,
                                                           lin1_b + i * 64, nullptr, m, N);
        agg_kernel<<<(N + 3) / 4, 256, 0, stream>>>(off, src_s, d_s, m,
                                                    ftab + (size_t)i * ROWS * 64, agg, N);
        mm64_kernel<true, false><<<mmg, 256, 0, stream>>>(agg, mlp_w1 + (size_t)i * 4096,
                                                          mlp_b1 + i * 64, nullptr, agg, N);
        mm64_kernel<false, true><<<mmg, 256, 0, stream>>>(agg, mlp_w2 + (size_t)i * 4096,
                                                          mlp_b2 + i * 64, x, x, N);
    }
    // post MLP: h = ssp(x@pw1+b1)@pw2+b2   (x dead afterwards, reuse buffers)
    mm64_kernel<true, false><<<mmg, 256, 0, stream>>>(x, post_w1, post_b1, nullptr, x, N);
    mm64_kernel<false, false><<<mmg, 256, 0, stream>>>(x, post_w2, post_b2, nullptr, m, N);

    pool_kernel<<<G, 64, 0, stream>>>(m, batch, pooled, N);
    post2_kernel<<<G, 128, 0, stream>>>(pooled, s4, solvent, p2w1, p2b1, p2w2, p2b2,
                                        p2w3, p2b3, out);
}

// Round 3
// 746.112 us; speedup vs baseline: 1.7157x; 1.3957x over previous
//
#include <hip/hip_runtime.h>
#include <hip/hip_bf16.h>

#define TABN   4096
#define ROWS   (TABN + 1)           // table rows per interaction
#define DMAX   6.5f
#define DELTA  (DMAX / (float)TABN)
#define INVD   ((float)TABN / DMAX)
#define LOG2F_ 0.6931471805599453f

__device__ __forceinline__ float ssp(float x) {
    // shifted softplus, numerically stable: log(1+e^x) - log(2)
    return fmaxf(x, 0.f) + log1pf(expf(-fabsf(x))) - LOG2F_;
}

// ---------------- filter lookup table: W_i(d) for d = t*DELTA ----------------
__global__ void ftab_kernel(const float* __restrict__ fw1, const float* __restrict__ fb1,
                            const float* __restrict__ fw2, const float* __restrict__ fb2,
                            float* __restrict__ ftab) {
    int t = blockIdx.x;          // 0..ROWS-1
    int i = blockIdx.y;          // interaction 0/1
    int j = threadIdx.x;         // 0..63 channel
    float d = (float)t * DELTA;
    float acc = fb1[i * 64 + j];
    for (int k = 0; k < 51; ++k) {
        float u = d - 0.1f * (float)k;
        float r = expf(-10.f * u * u);
        acc = fmaf(r, fw1[((size_t)i * 51 + k) * 64 + j], acc);
    }
    __shared__ float h[64];
    h[j] = ssp(acc);
    __syncthreads();
    float o = fb2[i * 64 + j];
    for (int k = 0; k < 64; ++k)
        o = fmaf(h[k], fw2[((size_t)i * 64 + k) * 64 + j], o);
    ftab[((size_t)i * ROWS + t) * 64 + j] = o;
}

// ---------------- per-edge distance + histogram of tgt ----------------
__global__ void edge_d_kernel(const float* __restrict__ pos, const int* __restrict__ ei,
                              float* __restrict__ d_arr, int* __restrict__ counts, int E) {
    int e = blockIdx.x * blockDim.x + threadIdx.x;
    if (e >= E) return;
    int s = ei[e], t = ei[E + e];
    float dx = pos[3 * s]     - pos[3 * t];
    float dy = pos[3 * s + 1] - pos[3 * t + 1];
    float dz = pos[3 * s + 2] - pos[3 * t + 2];
    d_arr[e] = sqrtf(dx * dx + dy * dy + dz * dz);
    atomicAdd(&counts[t], 1);
}

// ---------------- hierarchical exclusive scan over counts[n] ----------------
__global__ void scan1_kernel(const int* __restrict__ counts, int* __restrict__ bsums, int n) {
    int tid = threadIdx.x;
    int base = blockIdx.x * 1024 + tid * 4;
    int s = 0;
#pragma unroll
    for (int i = 0; i < 4; ++i) { int idx = base + i; if (idx < n) s += counts[idx]; }
    __shared__ int sm[256];
    sm[tid] = s;
    __syncthreads();
    for (int o = 128; o >= 1; o >>= 1) {
        if (tid < o) sm[tid] += sm[tid + o];
        __syncthreads();
    }
    if (tid == 0) bsums[blockIdx.x] = sm[0];
}

__global__ void scan2_kernel(int* __restrict__ bsums, int nb) {
    __shared__ int sm[1024];
    int tid = threadIdx.x;
    int v = (tid < nb) ? bsums[tid] : 0;
    sm[tid] = v;
    __syncthreads();
    for (int o = 1; o < 1024; o <<= 1) {
        int t = (tid >= o) ? sm[tid - o] : 0;
        __syncthreads();
        sm[tid] += t;
        __syncthreads();
    }
    if (tid < nb) bsums[tid] = sm[tid] - v;   // exclusive
}

__global__ void scan3_kernel(const int* __restrict__ counts, const int* __restrict__ bsums,
                             int* __restrict__ off, int* __restrict__ cursor, int n) {
    int tid = threadIdx.x;
    int base = blockIdx.x * 1024 + tid * 4;
    int c[4];
    int s = 0;
#pragma unroll
    for (int i = 0; i < 4; ++i) {
        int idx = base + i;
        c[i] = (idx < n) ? counts[idx] : 0;
        s += c[i];
    }
    __shared__ int sm[256];
    sm[tid] = s;
    __syncthreads();
    for (int o = 1; o < 256; o <<= 1) {
        int t = (tid >= o) ? sm[tid - o] : 0;
        __syncthreads();
        sm[tid] += t;
        __syncthreads();
    }
    int run = bsums[blockIdx.x] + sm[tid] - s;
#pragma unroll
    for (int i = 0; i < 4; ++i) {
        int idx = base + i;
        if (idx < n) { off[idx] = run; cursor[idx] = run; run += c[i]; }
    }
    if (blockIdx.x == gridDim.x - 1 && tid == 255) off[n] = run;
}

// ---------------- scatter edges into tgt-sorted order ----------------
__global__ void scatter_kernel(const int* __restrict__ ei, const float* __restrict__ d_arr,
                               int* __restrict__ cursor, int* __restrict__ src_s,
                               float* __restrict__ d_s, int E) {
    int e = blockIdx.x * blockDim.x + threadIdx.x;
    if (e >= E) return;
    int t = ei[E + e];
    int p = atomicAdd(&cursor[t], 1);
    src_s[p] = ei[e];
    d_s[p]   = d_arr[e];
}

// ---------------- x = emb_z[z] ----------------
__global__ void embed_kernel(const int* __restrict__ z, const float* __restrict__ emb,
                             float* __restrict__ x, int n) {
    int idx = blockIdx.x * blockDim.x + threadIdx.x;   // over n*16 float4 chunks
    if (idx >= n * 16) return;
    int node = idx >> 4, c = idx & 15;
    ((float4*)x)[idx] = ((const float4*)emb)[z[node] * 16 + c];
}

// ---------------- solvent head for the 4 unique solvent rows ----------------
__global__ void solv_kernel(const float* __restrict__ emb_solv,
                            const float* __restrict__ w1, const float* __restrict__ b1,
                            const float* __restrict__ w2, const float* __restrict__ b2,
                            float* __restrict__ s4) {
    __shared__ float h[4][64];
    int t = threadIdx.x, r = t >> 6, j = t & 63;
    float acc = b1[j];
    for (int k = 0; k < 64; ++k) acc = fmaf(emb_solv[r * 64 + k], w1[k * 64 + j], acc);
    h[r][j] = ssp(acc);
    __syncthreads();
    if (j < 32) {
        float a = b2[j];
        for (int k = 0; k < 64; ++k) a = fmaf(h[r][k], w2[k * 32 + j], a);
        s4[r * 32 + j] = a;
    }
}

// ------------- single [n,64]@[64,64]+b, weights via scalar loads ------------
// one thread per node; x row in VGPRs; w/b indices wave-uniform -> s_load
template <bool ACT>
__global__ void mm1_kernel(const float* __restrict__ in, const float* __restrict__ w,
                           const float* __restrict__ b, float* __restrict__ out, int n) {
    int node = blockIdx.x * 256 + threadIdx.x;
    node = min(node, n - 1);                    // no divergent return
    float x[64];
    const float4* in4 = (const float4*)(in + (size_t)node * 64);
#pragma unroll
    for (int c = 0; c < 16; ++c) {
        float4 v = in4[c];
        x[4 * c] = v.x; x[4 * c + 1] = v.y; x[4 * c + 2] = v.z; x[4 * c + 3] = v.w;
    }
    float4* o4 = (float4*)(out + (size_t)node * 64);
#pragma unroll 1
    for (int jg = 0; jg < 16; ++jg) {
        float4 acc = make_float4(b[jg * 4], b[jg * 4 + 1], b[jg * 4 + 2], b[jg * 4 + 3]);
#pragma unroll
        for (int k = 0; k < 64; ++k) {
            const float* wr = w + k * 64 + jg * 4;
            acc.x = fmaf(x[k], wr[0], acc.x);
            acc.y = fmaf(x[k], wr[1], acc.y);
            acc.z = fmaf(x[k], wr[2], acc.z);
            acc.w = fmaf(x[k], wr[3], acc.w);
        }
        if constexpr (ACT) {
            acc.x = ssp(acc.x); acc.y = ssp(acc.y); acc.z = ssp(acc.z); acc.w = ssp(acc.w);
        }
        o4[jg] = acc;
    }
}

// ------- fused 2-layer: out = ssp(in@W1+b1)@W2+b2 (+ res) -------------------
template <bool RES>
__global__ void mm2_kernel(const float* __restrict__ in,
                           const float* __restrict__ w1, const float* __restrict__ b1,
                           const float* __restrict__ w2, const float* __restrict__ b2,
                           const float* __restrict__ res, float* __restrict__ out, int n) {
    int node = blockIdx.x * 256 + threadIdx.x;
    node = min(node, n - 1);
    float x[64];
    const float4* in4 = (const float4*)(in + (size_t)node * 64);
#pragma unroll
    for (int c = 0; c < 16; ++c) {
        float4 v = in4[c];
        x[4 * c] = v.x; x[4 * c + 1] = v.y; x[4 * c + 2] = v.z; x[4 * c + 3] = v.w;
    }
    float h[64];
#pragma unroll 1
    for (int jg = 0; jg < 16; ++jg) {
        float4 acc = make_float4(b1[jg * 4], b1[jg * 4 + 1], b1[jg * 4 + 2], b1[jg * 4 + 3]);
#pragma unroll
        for (int k = 0; k < 64; ++k) {
            const float* wr = w1 + k * 64 + jg * 4;
            acc.x = fmaf(x[k], wr[0], acc.x);
            acc.y = fmaf(x[k], wr[1], acc.y);
            acc.z = fmaf(x[k], wr[2], acc.z);
            acc.w = fmaf(x[k], wr[3], acc.w);
        }
        h[jg * 4]     = ssp(acc.x);
        h[jg * 4 + 1] = ssp(acc.y);
        h[jg * 4 + 2] = ssp(acc.z);
        h[jg * 4 + 3] = ssp(acc.w);
    }
    const float4* r4 = (const float4*)(res + (size_t)node * 64);
    float4* o4 = (float4*)(out + (size_t)node * 64);
#pragma unroll 1
    for (int jg = 0; jg < 16; ++jg) {
        float4 acc = make_float4(b2[jg * 4], b2[jg * 4 + 1], b2[jg * 4 + 2], b2[jg * 4 + 3]);
#pragma unroll
        for (int k = 0; k < 64; ++k) {
            const float* wr = w2 + k * 64 + jg * 4;
            acc.x = fmaf(h[k], wr[0], acc.x);
            acc.y = fmaf(h[k], wr[1], acc.y);
            acc.z = fmaf(h[k], wr[2], acc.z);
            acc.w = fmaf(h[k], wr[3], acc.w);
        }
        if constexpr (RES) {
            float4 rv = r4[jg];
            acc.x += rv.x; acc.y += rv.y; acc.z += rv.z; acc.w += rv.w;
        }
        o4[jg] = acc;
    }
}

// ---------------- per-node aggregation: agg[t] = sum_e m[src]*W(d) ----------
// wave per tgt node, lane = channel; 4-deep unroll for memory-level parallelism
__global__ void agg_kernel(const int* __restrict__ off, const int* __restrict__ src_s,
                           const float* __restrict__ d_s, const float* __restrict__ m,
                           const float* __restrict__ ftab, float* __restrict__ agg, int n) {
    int wave = (blockIdx.x * blockDim.x + threadIdx.x) >> 6;
    int lane = threadIdx.x & 63;
    if (wave >= n) return;
    int e0 = off[wave], e1 = off[wave + 1];
    float acc0 = 0.f, acc1 = 0.f, acc2 = 0.f, acc3 = 0.f;
    int e = e0;
    for (; e + 4 <= e1; e += 4) {
        int s0 = src_s[e], s1 = src_s[e + 1], s2 = src_s[e + 2], s3 = src_s[e + 3];
        float m0 = m[(size_t)s0 * 64 + lane];
        float m1 = m[(size_t)s1 * 64 + lane];
        float m2 = m[(size_t)s2 * 64 + lane];
        float m3 = m[(size_t)s3 * 64 + lane];
        float dd0 = d_s[e], dd1 = d_s[e + 1], dd2 = d_s[e + 2], dd3 = d_s[e + 3];
        float ds0 = fminf(dd0, DMAX) * INVD, ds1 = fminf(dd1, DMAX) * INVD;
        float ds2 = fminf(dd2, DMAX) * INVD, ds3 = fminf(dd3, DMAX) * INVD;
        int t0 = min((int)ds0, TABN - 1), t1 = min((int)ds1, TABN - 1);
        int t2 = min((int)ds2, TABN - 1), t3 = min((int)ds3, TABN - 1);
        float f0 = ds0 - (float)t0, f1 = ds1 - (float)t1;
        float f2 = ds2 - (float)t2, f3 = ds3 - (float)t3;
        const float* p0 = ftab + (size_t)t0 * 64 + lane;
        const float* p1 = ftab + (size_t)t1 * 64 + lane;
        const float* p2 = ftab + (size_t)t2 * 64 + lane;
        const float* p3 = ftab + (size_t)t3 * 64 + lane;
        float a0 = p0[0], b0 = p0[64];
        float a1 = p1[0], b1 = p1[64];
        float a2 = p2[0], b2 = p2[64];
        float a3 = p3[0], b3 = p3[64];
        float w0 = fmaf(f0, b0 - a0, a0);
        float w1 = fmaf(f1, b1 - a1, a1);
        float w2 = fmaf(f2, b2 - a2, a2);
        float w3 = fmaf(f3, b3 - a3, a3);
        acc0 = fmaf(m0, w0, acc0);
        acc1 = fmaf(m1, w1, acc1);
        acc2 = fmaf(m2, w2, acc2);
        acc3 = fmaf(m3, w3, acc3);
    }
    for (; e < e1; ++e) {
        int   s  = src_s[e];
        float mm = m[(size_t)s * 64 + lane];
        float dd = d_s[e];
        float ds = fminf(dd, DMAX) * INVD;
        int   ti = min((int)ds, TABN - 1);
        float fr = ds - (float)ti;
        const float* r0 = ftab + (size_t)ti * 64 + lane;
        float w0 = r0[0], w1 = r0[64];
        acc0 = fmaf(mm, fmaf(fr, w1 - w0, w0), acc0);
    }
    agg[(size_t)wave * 64 + lane] = (acc0 + acc1) + (acc2 + acc3);
}

// ---------------- scatter-mean pooling via binary search (batch sorted) -----
__global__ void pool_kernel(const float* __restrict__ h, const int* __restrict__ batch,
                            float* __restrict__ pooled, int n_nodes) {
    int g = blockIdx.x, j = threadIdx.x;   // block = 64
    int lo = 0, hi = n_nodes;
    while (lo < hi) { int mid = (lo + hi) >> 1; if (batch[mid] < g) lo = mid + 1; else hi = mid; }
    int start = lo;
    int lo2 = start, hi2 = n_nodes;
    while (lo2 < hi2) { int mid = (lo2 + hi2) >> 1; if (batch[mid] < g + 1) lo2 = mid + 1; else hi2 = mid; }
    int end = lo2;
    float acc = 0.f;
    for (int r = start; r < end; ++r) acc += h[(size_t)r * 64 + j];
    float cnt = (float)(end - start);
    pooled[(size_t)g * 64 + j] = acc / fmaxf(cnt, 1.f);
}

// ---------------- final graph head: 96 -> 128 -> 32 -> 1 --------------------
__global__ void post2_kernel(const float* __restrict__ pooled, const float* __restrict__ s4,
                             const int* __restrict__ solvent,
                             const float* __restrict__ w1, const float* __restrict__ b1,
                             const float* __restrict__ w2, const float* __restrict__ b2,
                             const float* __restrict__ w3, const float* __restrict__ b3,
                             float* __restrict__ out) {
    __shared__ float in96[96];
    __shared__ float l1[128];
    __shared__ float l2[32];
    int g = blockIdx.x, t = threadIdx.x;   // block = 128
    if (t < 64)      in96[t] = pooled[(size_t)g * 64 + t];
    else if (t < 96) in96[t] = s4[solvent[g] * 32 + (t - 64)];
    __syncthreads();
    float acc = b1[t];
    for (int k = 0; k < 96; ++k) acc = fmaf(in96[k], w1[k * 128 + t], acc);
    l1[t] = ssp(acc);
    __syncthreads();
    if (t < 32) {
        float a = b2[t];
        for (int k = 0; k < 128; ++k) a = fmaf(l1[k], w2[k * 32 + t], a);
        l2[t] = ssp(a);
    }
    __syncthreads();
    if (t < 32) {
        float p = l2[t] * w3[t];
        for (int o = 16; o >= 1; o >>= 1) p += __shfl_down(p, o);
        if (t == 0) out[g] = p + b3[0];
    }
}

extern "C" void kernel_launch(void* const* d_in, const int* in_sizes, int n_in,
                              void* d_out, int out_size, void* d_ws, size_t ws_size,
                              hipStream_t stream) {
    const float* pos      = (const float*)d_in[0];
    const int*   ei       = (const int*)d_in[1];
    const int*   z        = (const int*)d_in[2];
    const int*   batch    = (const int*)d_in[3];
    const int*   solvent  = (const int*)d_in[4];
    const float* emb_z    = (const float*)d_in[5];
    const float* emb_solv = (const float*)d_in[6];
    const float* solv_w1  = (const float*)d_in[7];  const float* solv_b1 = (const float*)d_in[8];
    const float* solv_w2  = (const float*)d_in[9];  const float* solv_b2 = (const float*)d_in[10];
    const float* lin1_w   = (const float*)d_in[11]; const float* lin1_b  = (const float*)d_in[12];
    const float* mlp_w1   = (const float*)d_in[13]; const float* mlp_b1  = (const float*)d_in[14];
    const float* mlp_w2   = (const float*)d_in[15]; const float* mlp_b2  = (const float*)d_in[16];
    const float* filt_w1  = (const float*)d_in[17]; const float* filt_b1 = (const float*)d_in[18];
    const float* filt_w2  = (const float*)d_in[19]; const float* filt_b2 = (const float*)d_in[20];
    const float* post_w1  = (const float*)d_in[21]; const float* post_b1 = (const float*)d_in[22];
    const float* post_w2  = (const float*)d_in[23]; const float* post_b2 = (const float*)d_in[24];
    const float* p2w1 = (const float*)d_in[25]; const float* p2b1 = (const float*)d_in[26];
    const float* p2w2 = (const float*)d_in[27]; const float* p2b2 = (const float*)d_in[28];
    const float* p2w3 = (const float*)d_in[29]; const float* p2b3 = (const float*)d_in[30];
    float* out = (float*)d_out;

    const int N = in_sizes[2];
    const int E = in_sizes[1] / 2;
    const int G = in_sizes[4];

    char* wp = (char*)d_ws;
    auto alloc = [&](size_t bytes) -> void* {
        void* r = (void*)wp;
        wp += (bytes + 255) & ~(size_t)255;
        return r;
    };
    float* d_edge = (float*)alloc((size_t)E * 4);
    int*   src_s  = (int*)  alloc((size_t)E * 4);
    float* d_s    = (float*)alloc((size_t)E * 4);
    int*   counts = (int*)  alloc((size_t)N * 4);
    int*   off    = (int*)  alloc((size_t)(N + 1) * 4);
    int*   cursor = (int*)  alloc((size_t)N * 4);
    int*   bsums  = (int*)  alloc(1024 * 4);
    float* ftab   = (float*)alloc((size_t)2 * ROWS * 64 * 4);
    float* s4     = (float*)alloc(4 * 32 * 4);
    float* x      = (float*)alloc((size_t)N * 64 * 4);
    float* m      = (float*)alloc((size_t)N * 64 * 4);
    float* agg    = (float*)alloc((size_t)N * 64 * 4);
    float* pooled = (float*)alloc((size_t)G * 64 * 4);
    (void)ws_size; (void)n_in; (void)out_size;

    hipMemsetAsync(counts, 0, (size_t)N * 4, stream);

    ftab_kernel<<<dim3(ROWS, 2), 64, 0, stream>>>(filt_w1, filt_b1, filt_w2, filt_b2, ftab);
    edge_d_kernel<<<(E + 255) / 256, 256, 0, stream>>>(pos, ei, d_edge, counts, E);
    int nb = (N + 1023) / 1024;
    scan1_kernel<<<nb, 256, 0, stream>>>(counts, bsums, N);
    scan2_kernel<<<1, 1024, 0, stream>>>(bsums, nb);
    scan3_kernel<<<nb, 256, 0, stream>>>(counts, bsums, off, cursor, N);
    scatter_kernel<<<(E + 255) / 256, 256, 0, stream>>>(ei, d_edge, cursor, src_s, d_s, E);
    embed_kernel<<<((size_t)N * 16 + 255) / 256, 256, 0, stream>>>(z, emb_z, x, N);
    solv_kernel<<<1, 256, 0, stream>>>(emb_solv, solv_w1, solv_b1, solv_w2, solv_b2, s4);

    int mmg = (N + 255) / 256;
    for (int i = 0; i < 2; ++i) {
        mm1_kernel<false><<<mmg, 256, 0, stream>>>(x, lin1_w + (size_t)i * 4096,
                                                   lin1_b + i * 64, m, N);
        agg_kernel<<<(N + 3) / 4, 256, 0, stream>>>(off, src_s, d_s, m,
                                                    ftab + (size_t)i * ROWS * 64, agg, N);
        mm2_kernel<true><<<mmg, 256, 0, stream>>>(agg, mlp_w1 + (size_t)i * 4096,
                                                  mlp_b1 + i * 64, mlp_w2 + (size_t)i * 4096,
                                                  mlp_b2 + i * 64, x, x, N);
    }
    // post MLP: h = ssp(x@pw1+b1)@pw2+b2
    mm2_kernel<false><<<mmg, 256, 0, stream>>>(x, post_w1, post_b1, post_w2, post_b2,
                                               nullptr, m, N);

    pool_kernel<<<G, 64, 0, stream>>>(m, batch, pooled, N);
    post2_kernel<<<G, 128, 0, stream>>>(pooled, s4, solvent, p2w1, p2b1, p2w2, p2b2,
                                        p2w3, p2b3, out);
}